// Round 5
// baseline (333.582 us; speedup 1.0000x reference)
//
#include <hip/hip_runtime.h>

// MPS classifier, MI355X gfx950. Round 11: SITE-PAIR FUSION.
// r10 post-mortem: B-bytes halved -> slower; LDS halved (r7) -> flat. The
// invariant is per-STEP serial overhead (lockstep waves: read->MFMA->epi->
// write->barrier), not any pipe. Fix: precompute G^(j)_de = M_j,d @ M_j+1,e
// (4 fused mats / site-pair, SAME bytes) so each step advances 2 sites:
//   L'' = sum_de phi_d(j+1)phi_e(j+2) * (L @ G_de)      (fwd)
//   R   = sum_de phi_d(j+1)phi_e(j+2) * (G_de @ R)      (bwd)
// Steps/barriers/state-LDS-round-trips/epilogues all halve per site; MFMA
// work and stream bytes unchanged. Products built on-device (504 x 128^3
// fp16 GEMMs, ~2 GFLOP). bwd products computed as G^T = Me^T @ Md^T so both
// directions use ONE packed B-op output path; main-kernel read indexing is
// IDENTICAL for fwd and bwd: base + de*2048 + (kt*8+w)*64 + lane.
// Main kernel per-wave state read/write index math kept verbatim from r10.

typedef _Float16 v8h __attribute__((ext_vector_type(8)));
typedef _Float16 h2  __attribute__((ext_vector_type(2)));
typedef float    v4f __attribute__((ext_vector_type(4)));

#define PI_HALF 1.5707963267948966f
#define STEP_U4    8192              // uint4 per pair-step: 4 de * 2048
#define FWD_SGL_U4 516096            // 63*8192
#define BWD_U4     520192            // FWD_SGL + 2*2048
#define BWD_SGL_U4 1036288           // BWD_U4 + 63*8192
#define WS_U4      1040384           // BWD_SGL + 2*2048
#define LOUT_F32   (WS_U4*4)         // = 4161536 (same as r10)
#define ROUT_F32   (LOUT_F32 + 8192*128)
#define PHI_S 66                     // phi row stride (u32)

union U4H8 { uint4 u; v8h h; };

__device__ __forceinline__ v4f mfma16h(uint4 a, uint4 b, v4f c){
  U4H8 ua, ub; ua.u = a; ub.u = b;
  return __builtin_amdgcn_mfma_f32_16x16x32_f16(ua.h, ub.h, c, 0, 0, 0);
}
__device__ __forceinline__ unsigned pack2h(float lo, float hi){
  h2 p; p[0] = (_Float16)lo; p[1] = (_Float16)hi;
  return __builtin_bit_cast(unsigned, p);
}
__device__ __forceinline__ unsigned short f16b(float v){
  return __builtin_bit_cast(unsigned short, (_Float16)v);
}

// ---------------------------------------------------------------------------
// repack_products: WGs 0..251 fwd products, 252..503 bwd products, 504..507
// singles (mid 126 fwd B-op layout / mid 127 bwd A-op layout).
// Product WG: stage A-frags + B-frags (fp16) in LDS, 128x128x128 MFMA,
// write packed B-op frags: (lane,jj) = C[k=32kt+8(lane>>4)+jj][n=16nt+(lane&15)].
//   fwd (G):   A = M_j,d (k-contig),     B = M_j+1,e (n-contig)
//   bwd (G^T): A = M_j+1,e^T (row-contig), B = M_j,d^T (k-contig)
// ---------------------------------------------------------------------------
__global__ __launch_bounds__(256) void repack_products(const float* __restrict__ mid,
                                                       unsigned short* __restrict__ wsB){
  const int wg  = blockIdx.x;
  const int tid = threadIdx.x;
  const int lg  = tid & 15, l3 = lg & 3, q = lg >> 2;
  const int oi  = tid >> 4;          // 0..15
  const int ot  = oi >> 1;           // 0..7  (am or nt)
  const int h   = oi & 1;

  __shared__ unsigned Afr[8192];     // 32 KB, frag (am*4+kt)
  __shared__ unsigned Bfr[8192];     // 32 KB, frag (kt*8+nt)

  // src(outer,k), k contiguous -> frag layout
  auto stageP1 = [&](unsigned* dst, const float* src, bool isA){
    #pragma unroll
    for (int c = 0; c < 2; ++c){
      const int kt = 2*h + c;
      const int k0 = 32*kt + 8*q;
      #pragma unroll
      for (int mp = 0; mp < 4; ++mp){
        const int outer = 16*ot + 4*l3 + mp;
        const float* s = src + (size_t)outer*256 + k0;
        float4 a = *(const float4*)s;
        float4 b = *(const float4*)(s + 4);
        const int frag = isA ? (ot*4 + kt) : (kt*8 + ot);
        unsigned* o = dst + (frag*64 + 16*q + 4*l3 + mp)*4;
        o[0]=pack2h(a.x,a.y); o[1]=pack2h(a.z,a.w);
        o[2]=pack2h(b.x,b.y); o[3]=pack2h(b.z,b.w);
      }
    }
  };
  // src(k,outer), outer contiguous -> frag layout
  auto stageP2 = [&](unsigned* dst, const float* src, bool isA){
    #pragma unroll
    for (int c = 0; c < 2; ++c){
      const int kt = 2*h + c;
      const int o0 = 16*ot + 4*l3;
      float V[8][4];
      #pragma unroll
      for (int jj = 0; jj < 8; ++jj){
        const int k = 32*kt + 8*q + jj;
        float4 a = *(const float4*)(src + (size_t)k*256 + o0);
        V[jj][0]=a.x; V[jj][1]=a.y; V[jj][2]=a.z; V[jj][3]=a.w;
      }
      const int frag = isA ? (ot*4 + kt) : (kt*8 + ot);
      #pragma unroll
      for (int t = 0; t < 4; ++t){
        unsigned* o = dst + (frag*64 + 16*q + 4*l3 + t)*4;
        o[0]=pack2h(V[0][t],V[1][t]); o[1]=pack2h(V[2][t],V[3][t]);
        o[2]=pack2h(V[4][t],V[5][t]); o[3]=pack2h(V[6][t],V[7][t]);
      }
    }
  };

  if (wg >= 504){
    // singles: direct format conversion to global
    const int ss = wg - 504, half = ss >> 1, d = ss & 1;
    if (half == 0){
      unsigned* dst = (unsigned*)((uint4*)wsB + FWD_SGL_U4 + d*2048);
      stageP2(dst, mid + (size_t)126*32768 + d*128, false);   // B-op of M126_d
    } else {
      unsigned* dst = (unsigned*)((uint4*)wsB + BWD_SGL_U4 + d*2048);
      stageP1(dst, mid + (size_t)127*32768 + d*128, true);    // A-op of M127_d
    }
    return;
  }

  const bool isf = wg < 252;
  const int idx  = isf ? wg : wg - 252;
  const int step = idx >> 2, de = idx & 3, d = de >> 1, e = de & 1;
  const int j    = isf ? 2*step : 252 - 2*step;

  if (isf){
    stageP1(Afr, mid + (size_t)j*32768 + d*128, true);        // M_j,d (row l, k m)
    stageP2(Bfr, mid + (size_t)(j+1)*32768 + e*128, false);   // M_j+1,e (k m, n r)
  } else {
    stageP2(Afr, mid + (size_t)(j+1)*32768 + e*128, true);    // M_j+1,e^T (row r, k m)
    stageP1(Bfr, mid + (size_t)j*32768 + d*128, false);       // M_j,d^T (k m, n l)
  }
  __syncthreads();

  const int w = tid >> 6, lane = tid & 63, r = lane & 15, qq = lane >> 4;
  v4f acc[2][8] = {};
  #pragma unroll
  for (int kt = 0; kt < 4; ++kt){
    uint4 a0 = *(const uint4*)&Afr[(((2*w+0)*4 + kt)*64 + lane)*4];
    uint4 a1 = *(const uint4*)&Afr[(((2*w+1)*4 + kt)*64 + lane)*4];
    #pragma unroll
    for (int nt = 0; nt < 8; ++nt){
      uint4 b = *(const uint4*)&Bfr[((kt*8 + nt)*64 + lane)*4];
      acc[0][nt] = mfma16h(a0, b, acc[0][nt]);
      acc[1][nt] = mfma16h(a1, b, acc[1][nt]);
    }
  }

  const size_t dstU4 = (isf ? 0 : BWD_U4) + (size_t)step*STEP_U4 + de*2048;
  uint2* gp = (uint2*)((uint4*)wsB + dstU4);
  #pragma unroll
  for (int i = 0; i < 2; ++i){
    const int lane_i = 16*(2*i + (qq >> 1)) + r;
    #pragma unroll
    for (int nt = 0; nt < 8; ++nt){
      unsigned w0 = pack2h(acc[i][nt][0], acc[i][nt][1]);
      unsigned w1 = pack2h(acc[i][nt][2], acc[i][nt][3]);
      gp[((w*8 + nt)*64 + lane_i)*2 + (qq & 1)] = make_uint2(w0, w1);
    }
  }
}

// ---------------------------------------------------------------------------
// Main kernel: dir = bid>>7 (0 fwd, 1 bwd), rg = bid&127 (rows 64*rg..+64).
// 63 pair-bodies + 1 single-body per direction. State frags + swizzle and all
// per-wave index math identical to r10.
// ---------------------------------------------------------------------------
__global__ __launch_bounds__(512, 2) void mps_main(
    const float* __restrict__ x,               // [8192][256]
    const float* __restrict__ first,           // [2][128]
    const unsigned short* __restrict__ wsBv,   // product frags
    const float* __restrict__ lastw,           // [128][2]
    float* __restrict__ ws_out)                // float view of workspace
{
  __shared__ unsigned phiL[128*PHI_S];        // 33.8 KB
  __shared__ unsigned Ast[2*16*64*4];         // 32 KB state dbuf

  const int tid  = threadIdx.x;
  const int bid  = blockIdx.x;
  const int dir  = bid >> 7;
  const int rg   = bid & 127;
  const int w    = tid >> 6;
  const int lane = tid & 63;
  const int r    = lane & 15;
  const int q    = lane >> 4;
  const int rh   = r >> 3;
  const int rowbase = rg * 64;
  const int physL = lane ^ ((lane >> 3) & 7);

  // ---- Phase 1: feature map -> this direction's 128 phi rows ----
  {
    const int row = tid >> 3;            // 0..63
    const int c   = tid & 7;             // 32-site chunk
    const float4* xp = (const float4*)(x + (size_t)(rowbase + row) * 256 + c*32);
    float xv[32];
    float vmin = 3.0e38f, vmax = -3.0e38f;
    #pragma unroll
    for (int cc = 0; cc < 8; ++cc){
      float4 u = xp[cc];
      xv[cc*4+0] = u.x; xv[cc*4+1] = u.y; xv[cc*4+2] = u.z; xv[cc*4+3] = u.w;
      vmin = fminf(vmin, fminf(fminf(u.x,u.y), fminf(u.z,u.w)));
      vmax = fmaxf(vmax, fmaxf(fmaxf(u.x,u.y), fmaxf(u.z,u.w)));
    }
    #pragma unroll
    for (int m = 1; m < 8; m <<= 1){
      vmin = fminf(vmin, __shfl_xor(vmin, m));
      vmax = fmaxf(vmax, __shfl_xor(vmax, m));
    }
    const float sc = PI_HALF / (vmax - vmin + 1e-6f);
    const bool mine = dir ? (c >= 4) : (c < 4);
    if (mine){
      const int s0 = 32*c - (dir ? 128 : 0);
      #pragma unroll
      for (int j = 0; j < 32; ++j){
        float a = (xv[j] - vmin) * sc;
        phiL[(s0 + j)*PHI_S + row] = pack2h(__cosf(a), __sinf(a));
      }
    }
  }
  __syncthreads();

  // ---- State init (buf 0) + step-0 prefetch ----
  uint4 F0[16], F1[16];    // streamed G-frags ping-pong: [de*4 + kt]
  if (dir == 0){
    const int mt = w >> 1;
    #pragma unroll
    for (int cc = 0; cc < 2; ++cc){
      const int kt = 2*(w & 1) + cc;
      const int m  = 16*mt + r;
      h2 p0 = __builtin_bit_cast(h2, phiL[0*PHI_S + m]);
      const float c0 = (float)p0[0], s0 = (float)p0[1];
      uint4 o; unsigned ow[4];
      #pragma unroll
      for (int jp = 0; jp < 4; ++jp){
        const int k = 32*kt + 8*q + 2*jp;
        float v0 = first[k]  *c0 + first[128+k]  *s0;
        float v1 = first[k+1]*c0 + first[128+k+1]*s0;
        ow[jp] = pack2h(v0, v1);
      }
      o.x=ow[0]; o.y=ow[1]; o.z=ow[2]; o.w=ow[3];
      *(uint4*)&Ast[((mt*4 + kt)*64 + physL)*4] = o;
    }
  } else {
    const int kt = w >> 1;
    #pragma unroll
    for (int cc = 0; cc < 2; ++cc){
      const int nt = 2*(w & 1) + cc;
      const int n  = 16*nt + r;
      h2 p5 = __builtin_bit_cast(h2, phiL[127*PHI_S + n]);
      const float cb = (float)p5[0], sb = (float)p5[1];
      uint4 o; unsigned ow[4];
      #pragma unroll
      for (int jp = 0; jp < 4; ++jp){
        const int k = 32*kt + 8*q + 2*jp;
        float2 g0 = *(const float2*)(lastw + 2*k);
        float2 g1 = *(const float2*)(lastw + 2*(k+1));
        ow[jp] = pack2h(g0.x*cb + g0.y*sb, g1.x*cb + g1.y*sb);
      }
      o.x=ow[0]; o.y=ow[1]; o.z=ow[2]; o.w=ow[3];
      *(uint4*)&Ast[((kt*4 + nt)*64 + physL)*4] = o;
    }
  }
  {
    const uint4* bp = (const uint4*)wsBv + (dir ? BWD_U4 : 0);
    #pragma unroll
    for (int de = 0; de < 4; ++de)
      #pragma unroll
      for (int kt = 0; kt < 4; ++kt)
        F0[de*4+kt] = bp[(size_t)de*2048 + (kt*8 + w)*64 + lane];
  }

  float* Lout = ws_out + LOUT_F32;
  float* Rout = ws_out + ROUT_F32;

  // ---- pair-step body ----
  auto body = [&](int p, uint4 (&Fc)[16], uint4 (&Fn)[16]){
    __syncthreads();

    // prefetch step p+1 (or the single-site mats at p==62)
    if (p < 62){
      const uint4* bp = (const uint4*)wsBv + (dir ? BWD_U4 : 0) + (size_t)(p+1)*STEP_U4;
      #pragma unroll
      for (int de = 0; de < 4; ++de)
        #pragma unroll
        for (int kt = 0; kt < 4; ++kt)
          Fn[de*4+kt] = bp[(size_t)de*2048 + (kt*8 + w)*64 + lane];
    } else {
      if (dir == 0){
        const uint4* bp = (const uint4*)wsBv + FWD_SGL_U4;
        #pragma unroll
        for (int d = 0; d < 2; ++d)
          #pragma unroll
          for (int kt = 0; kt < 4; ++kt)
            Fn[d*4+kt] = bp[(size_t)d*2048 + (kt*8 + w)*64 + lane];
      } else {
        const uint4* bp = (const uint4*)wsBv + BWD_SGL_U4;
        #pragma unroll
        for (int d = 0; d < 2; ++d)
          #pragma unroll
          for (int kt = 0; kt < 4; ++kt)
            Fn[d*4+kt] = bp[(size_t)d*2048 + (w*4 + kt)*64 + lane];
      }
    }

    v4f acc[4][4] = {};   // fwd: [mt][de]; bwd: [nt][de]
    const unsigned* Sb = &Ast[(p & 1) * 4096];
    #pragma unroll
    for (int kt = 0; kt < 4; ++kt){
      uint4 sfr[4];
      #pragma unroll
      for (int i = 0; i < 4; ++i){
        const int fi = (dir == 0) ? (i*4 + kt) : (kt*4 + i);
        sfr[i] = *(const uint4*)&Sb[(fi*64 + physL)*4];
      }
      #pragma unroll
      for (int de = 0; de < 4; ++de)
        #pragma unroll
        for (int i = 0; i < 4; ++i)
          acc[i][de] = (dir == 0) ? mfma16h(sfr[i], Fc[de*4+kt], acc[i][de])
                                  : mfma16h(Fc[de*4+kt], sfr[i], acc[i][de]);
    }

    unsigned short* Wb = (unsigned short*)&Ast[((p+1) & 1) * 4096];
    if (dir == 0){
      const int X  = 4*(w & 1) + 2*rh + (q >> 1);
      const int S0 = 32*(w & 1) + 16*rh + 4*q;
      const int i1 = 2*p + 1, i2 = 2*p + 2;
      #pragma unroll
      for (int mt = 0; mt < 4; ++mt){
        uint4 pA = *(const uint4*)&phiL[i1*PHI_S + 16*mt + 4*q];
        uint4 pB = *(const uint4*)&phiL[i2*PHI_S + 16*mt + 4*q];
        const unsigned prA[4] = {pA.x,pA.y,pA.z,pA.w};
        const unsigned prB[4] = {pB.x,pB.y,pB.z,pB.w};
        const int base = (mt*4 + (w >> 1))*512;
        #pragma unroll
        for (int reg = 0; reg < 4; ++reg){
          h2 hA = __builtin_bit_cast(h2, prA[reg]);
          h2 hB = __builtin_bit_cast(h2, prB[reg]);
          const float c1 = (float)hA[0], s1 = (float)hA[1];
          const float c2 = (float)hB[0], s2 = (float)hB[1];
          float v = (c1*c2)*acc[mt][0][reg] + (c1*s2)*acc[mt][1][reg]
                  + (s1*c2)*acc[mt][2][reg] + (s1*s2)*acc[mt][3][reg];
          Wb[base + ((S0 + reg) ^ X)*8 + (r & 7)] = f16b(v);
        }
      }
    } else {
      const int X = 4*(w & 1) + 2*(q >> 1) + rh;
      const int S = (32*(w & 1) + 16*(q >> 1) + r) ^ X;
      const int i1 = 125 - 2*p, i2 = 126 - 2*p;
      #pragma unroll
      for (int nt = 0; nt < 4; ++nt){
        h2 p1 = __builtin_bit_cast(h2, phiL[i1*PHI_S + 16*nt + r]);
        h2 p2 = __builtin_bit_cast(h2, phiL[i2*PHI_S + 16*nt + r]);
        const float k00 = (float)p1[0]*(float)p2[0];
        const float k01 = (float)p1[0]*(float)p2[1];
        const float k10 = (float)p1[1]*(float)p2[0];
        const float k11 = (float)p1[1]*(float)p2[1];
        const int base = ((w >> 1)*4 + nt)*512 + S*8 + 4*(q & 1);
        #pragma unroll
        for (int reg = 0; reg < 4; ++reg){
          float v = k00*acc[nt][0][reg] + k01*acc[nt][1][reg]
                  + k10*acc[nt][2][reg] + k11*acc[nt][3][reg];
          Wb[base + reg] = f16b(v);
        }
      }
    }
  };

  #pragma unroll 1
  for (int p = 0; p < 62; p += 2){
    body(p,     F0, F1);
    body(p + 1, F1, F0);
  }
  body(62, F0, F1);

  // ---- single-site final body (fwd: mid126+phi127 -> Lout; bwd: mid127+phi128 -> Rout)
  {
    __syncthreads();
    v4f acc[4][2] = {};
    const unsigned* Sb = &Ast[4096];   // buf 1
    #pragma unroll
    for (int kt = 0; kt < 4; ++kt){
      uint4 sfr[4];
      #pragma unroll
      for (int i = 0; i < 4; ++i){
        const int fi = (dir == 0) ? (i*4 + kt) : (kt*4 + i);
        sfr[i] = *(const uint4*)&Sb[(fi*64 + physL)*4];
      }
      #pragma unroll
      for (int d = 0; d < 2; ++d)
        #pragma unroll
        for (int i = 0; i < 4; ++i)
          acc[i][d] = (dir == 0) ? mfma16h(sfr[i], F1[d*4+kt], acc[i][d])
                                 : mfma16h(F1[d*4+kt], sfr[i], acc[i][d]);
    }
    if (dir == 0){
      #pragma unroll
      for (int mt = 0; mt < 4; ++mt){
        uint4 pA = *(const uint4*)&phiL[127*PHI_S + 16*mt + 4*q];
        const unsigned pr[4] = {pA.x,pA.y,pA.z,pA.w};
        #pragma unroll
        for (int reg = 0; reg < 4; ++reg){
          h2 ph = __builtin_bit_cast(h2, pr[reg]);
          float v = (float)ph[0]*acc[mt][0][reg] + (float)ph[1]*acc[mt][1][reg];
          Lout[(size_t)(rowbase + 16*mt + 4*q + reg)*128 + 16*w + r] = v;
        }
      }
    } else {
      #pragma unroll
      for (int nt = 0; nt < 4; ++nt){
        h2 ph = __builtin_bit_cast(h2, phiL[0*PHI_S + 16*nt + r]);
        const float cb = (float)ph[0], sb = (float)ph[1];
        float4 vv;
        vv.x = cb*acc[nt][0][0] + sb*acc[nt][1][0];
        vv.y = cb*acc[nt][0][1] + sb*acc[nt][1][1];
        vv.z = cb*acc[nt][0][2] + sb*acc[nt][1][2];
        vv.w = cb*acc[nt][0][3] + sb*acc[nt][1][3];
        *(float4*)(Rout + (size_t)rg*8192 + (16*nt + r)*128 + 16*w + 4*q) = vv;
      }
    }
  }
}

// ---------------------------------------------------------------------------
// Combine: scalar[b] = sum_l Lout[b][l]*RoutT[b>>6][b&63][l]; logits = s*w + b
// ---------------------------------------------------------------------------
__global__ __launch_bounds__(256) void combine(const float* __restrict__ ws,
                                               const float* __restrict__ wlin,
                                               const float* __restrict__ blin,
                                               float* __restrict__ out){
  const int t   = blockIdx.x * 256 + threadIdx.x;
  const int row = t >> 2;
  const int c   = t & 3;
  const float* Lp = ws + LOUT_F32 + (size_t)row*128 + c*32;
  const float* Rp = ws + ROUT_F32 + (size_t)(row >> 6)*8192 + (row & 63)*128 + c*32;
  float s = 0.0f;
  #pragma unroll
  for (int i = 0; i < 8; ++i){
    float4 a = ((const float4*)Lp)[i];
    float4 b = ((const float4*)Rp)[i];
    s += a.x*b.x + a.y*b.y + a.z*b.z + a.w*b.w;
  }
  s += __shfl_xor(s, 1);
  s += __shfl_xor(s, 2);
  if (c == 0){
    #pragma unroll
    for (int o = 0; o < 10; ++o)
      out[(size_t)row*10 + o] = s*wlin[o] + blin[o];
  }
}

extern "C" void kernel_launch(void* const* d_in, const int* in_sizes, int n_in,
                              void* d_out, int out_size, void* d_ws, size_t ws_size,
                              hipStream_t stream){
  (void)in_sizes; (void)n_in; (void)out_size; (void)ws_size;
  const float* x     = (const float*)d_in[0];
  const float* first = (const float*)d_in[1];
  const float* mid   = (const float*)d_in[2];
  const float* lastw = (const float*)d_in[3];
  const float* wlin  = (const float*)d_in[4];
  const float* blin  = (const float*)d_in[5];
  float* o            = (float*)d_out;
  unsigned short* wsB = (unsigned short*)d_ws;   // 16.26 MB product frags + L/R

  hipLaunchKernelGGL(repack_products, dim3(508), dim3(256), 0, stream, mid, wsB);
  hipLaunchKernelGGL(mps_main,        dim3(256), dim3(512), 0, stream,
                     x, first, wsB, lastw, (float*)d_ws);
  hipLaunchKernelGGL(combine,         dim3(128), dim3(256), 0, stream,
                     (const float*)d_ws, wlin, blin, o);
}

// Round 6
// 274.191 us; speedup vs baseline: 1.2166x; 1.2166x over previous
//
#include <hip/hip_runtime.h>

// MPS classifier, MI355X gfx950. Round 12: r9 bidirectional structure at
// 4 waves/SIMD. r11 post-mortem: pair-fusion broke the B ping-pong (needed
// 128 VGPR, got 116) -> serialized stream, 4.1us/step. Reverted.
// This round: 1024-thread WGs, 16 waves. Waves 0-7 fwd (16-col strips of
// left'[32b x 128l]); waves 8-15 bwd (16-row strips of R[128l x 32b]).
// Per-CU B traffic UNCHANGED (exclusive strips, 16.6 MB); per-wave chain
// halves; 4 waves/SIMD x 2 directions cover latency. Repack = r10's
// half-size version (fwd B-op sites 0..126, bwd A-op-T sites 127..253).
// In-WG middle combine (no Lout/Rout roundtrip, no 3rd kernel).

typedef _Float16 v8h __attribute__((ext_vector_type(8)));
typedef _Float16 h2  __attribute__((ext_vector_type(2)));
typedef float    v4f __attribute__((ext_vector_type(4)));

#define PI_HALF 1.5707963267948966f
#define SITE_U4 4096                 // uint4 per site: 2 planes * 32 frags * 64... (2*4*8*64)
#define TOFF_U4 (127*4096)           // bwd (transposed) half base, in uint4

union U4H8 { uint4 u; v8h h; };

__device__ __forceinline__ v4f mfma16h(uint4 a, uint4 b, v4f c){
  U4H8 ua, ub; ua.u = a; ub.u = b;
  return __builtin_amdgcn_mfma_f32_16x16x32_f16(ua.h, ub.h, c, 0, 0, 0);
}
__device__ __forceinline__ unsigned pack2h(float lo, float hi){
  h2 p; p[0] = (_Float16)lo; p[1] = (_Float16)hi;
  return __builtin_bit_cast(unsigned, p);
}
__device__ __forceinline__ unsigned short f16b(float v){
  return __builtin_bit_cast(unsigned short, (_Float16)v);
}

// ---------------------------------------------------------------------------
// Repack mid (fp32 [254][128][2][128]) — r10's verbatim.
// Blocks 0..507   (sites 0..126)  -> fwd B-op frags [site][d][kt4][nt8][64]:
//   (lane,j) = mid[site][k=32kt+8(lane>>4)+j][d][n=16nt+(lane&15)]
// Blocks 508..1015 (sites 127..253)-> bwd A-op frags at TOFF [srel][d][am8][kt4][64]:
//   (lane,j) = mid[site][m=16am+(lane&15)][d][k=32kt+8(lane>>4)+j]
// ---------------------------------------------------------------------------
__global__ __launch_bounds__(256) void repack_mid(const float* __restrict__ mid,
                                                  unsigned short* __restrict__ wsB){
  const int bid = blockIdx.x;
  if (bid < 508){
    int idx  = bid * 256 + threadIdx.x;
    int lg   = idx & 15;
    int nt   = (idx >> 4) & 7;
    int kt   = (idx >> 7) & 3;
    int d    = (idx >> 9) & 1;
    int site = idx >> 10;            // 0..126
    int q    = lg >> 2;
    int n0   = 16*nt + 4*(lg & 3);
    const float* src = mid + ((size_t)(site*128 + 32*kt + 8*q)*2 + d)*128 + n0;
    float V[8][4];
    #pragma unroll
    for (int j = 0; j < 8; ++j){
      float4 a = *(const float4*)(src + (size_t)j*256);
      V[j][0]=a.x; V[j][1]=a.y; V[j][2]=a.z; V[j][3]=a.w;
    }
    uint4* dst = (uint4*)wsB + ((((size_t)site*2 + d)*4 + kt)*8 + nt)*64
               + 16*q + 4*(lg & 3);
    #pragma unroll
    for (int t = 0; t < 4; ++t){
      uint4 o;
      o.x = pack2h(V[0][t], V[1][t]);
      o.y = pack2h(V[2][t], V[3][t]);
      o.z = pack2h(V[4][t], V[5][t]);
      o.w = pack2h(V[6][t], V[7][t]);
      dst[t] = o;
    }
  } else {
    int idx  = (bid - 508) * 256 + threadIdx.x;
    int lg   = idx & 15;
    int kt   = (idx >> 4) & 3;
    int am   = (idx >> 6) & 7;
    int d    = (idx >> 9) & 1;
    int srel = idx >> 10;            // 0..126
    int site = 127 + srel;
    int q    = lg >> 2;
    int m0   = 16*am + 4*(lg & 3);
    int k0   = 32*kt + 8*q;
    uint4* dst = (uint4*)wsB + TOFF_U4
               + ((((size_t)srel*2 + d)*8 + am)*4 + kt)*64 + 16*q + 4*(lg & 3);
    #pragma unroll
    for (int mp = 0; mp < 4; ++mp){
      const float* src = mid + ((size_t)((site*128 + m0 + mp)*2) + d)*128 + k0;
      float4 a = *(const float4*)(src);
      float4 b = *(const float4*)(src + 4);
      uint4 o;
      o.x = pack2h(a.x, a.y);
      o.y = pack2h(a.z, a.w);
      o.z = pack2h(b.x, b.y);
      o.w = pack2h(b.z, b.w);
      dst[mp] = o;
    }
  }
}

// ---------------------------------------------------------------------------
// Main kernel: 256 WGs x 1024 threads (16 waves), 32 rows/WG, 1 WG/CU
// (LDS 86.6 KB > 80 KB blocks co-residency). Waves 0..7 fwd, 8..15 bwd.
// LDS: phiT[256][36] packed f16; Af/Rf state dbufs 16 KB each; Rcomb; scal.
// Slot swizzle: phys = S ^ ((S>>3)&7) on both write and read.
// ---------------------------------------------------------------------------
__global__ __launch_bounds__(1024, 4) void mps_main(
    const float* __restrict__ x,               // [8192][256]
    const float* __restrict__ first,           // [2][128]
    const unsigned short* __restrict__ wsBv,   // repacked mid frags
    const float* __restrict__ lastw,           // [128][2]
    const float* __restrict__ wlin,            // [10]
    const float* __restrict__ blin,            // [10]
    float* __restrict__ out)                   // [8192][10]
{
  __shared__ unsigned phiT[256*36];        // 36 KB
  __shared__ unsigned Af[2*8*64*4];        // 16 KB [buf][frag=mt*4+kt][slot][word]
  __shared__ unsigned Rf[2*8*64*4];        // 16 KB [buf][frag=kt*2+nt][slot][word]
  __shared__ float Rcomb[128*33];          // 16.9 KB
  __shared__ float scal[32];

  const int tid  = threadIdx.x;
  const int gblk = blockIdx.x;
  const int w    = tid >> 6;               // 0..7 fwd, 8..15 bwd
  const int lane = tid & 63;
  const int r    = lane & 15;
  const int q    = lane >> 4;
  const int rh   = r >> 3;
  const int rowbase = gblk * 32;
  const int physL = lane ^ ((lane >> 3) & 7);

  // ---- Phase 1: feature map -> packed f16 (cos,sin) table (all 256 sites) ----
  {
    const int row = tid >> 5;              // 0..31
    const int c0  = (tid & 31) * 8;        // 8-site chunk
    const float4* xp = (const float4*)(x + (size_t)(rowbase + row) * 256 + c0);
    float xv[8];
    float vmin = 3.0e38f, vmax = -3.0e38f;
    #pragma unroll
    for (int c = 0; c < 2; ++c){
      float4 u = xp[c];
      xv[c*4+0] = u.x; xv[c*4+1] = u.y; xv[c*4+2] = u.z; xv[c*4+3] = u.w;
      vmin = fminf(vmin, fminf(fminf(u.x,u.y), fminf(u.z,u.w)));
      vmax = fmaxf(vmax, fmaxf(fmaxf(u.x,u.y), fmaxf(u.z,u.w)));
    }
    #pragma unroll
    for (int m = 1; m < 32; m <<= 1){
      vmin = fminf(vmin, __shfl_xor(vmin, m));
      vmax = fmaxf(vmax, __shfl_xor(vmax, m));
    }
    const float sc = PI_HALF / (vmax - vmin + 1e-6f);
    #pragma unroll
    for (int j = 0; j < 8; ++j){
      float a = (xv[j] - vmin) * sc;
      phiT[(c0 + j)*36 + row] = pack2h(__cosf(a), __sinf(a));
    }
  }
  __syncthreads();

  // ---- State init (buf 0) + step-0 stream prefetch ----
  uint4 F0[8], F1[8];     // streamed operand ping-pong: [d*4 + kt]
  if (w < 8){
    // L1[b][l] = c0(b)*first0[l] + s0(b)*first1[l]; wave w -> frag (mt=w>>2, kt=w&3)
    const int mt = w >> 2, kt = w & 3;
    float f0[8], f1[8];
    #pragma unroll
    for (int j = 0; j < 8; ++j){
      int l = 32*kt + 8*q + j;
      f0[j] = first[l]; f1[j] = first[128 + l];
    }
    h2 p0 = __builtin_bit_cast(h2, phiT[0*36 + 16*mt + r]);
    const float c0 = (float)p0[0], s0 = (float)p0[1];
    uint4 o;
    o.x = pack2h(f0[0]*c0 + f1[0]*s0, f0[1]*c0 + f1[1]*s0);
    o.y = pack2h(f0[2]*c0 + f1[2]*s0, f0[3]*c0 + f1[3]*s0);
    o.z = pack2h(f0[4]*c0 + f1[4]*s0, f0[5]*c0 + f1[5]*s0);
    o.w = pack2h(f0[6]*c0 + f1[6]*s0, f0[7]*c0 + f1[7]*s0);
    *(uint4*)&Af[((mt*4 + kt)*64 + physL)*4] = o;
    // prefetch fwd B(site 0): wave's 16-col strip (nt = w), both planes
    const uint4* bp = (const uint4*)wsBv;
    #pragma unroll
    for (int d = 0; d < 2; ++d)
      #pragma unroll
      for (int kk = 0; kk < 4; ++kk)
        F0[d*4+kk] = bp[(size_t)((d*4 + kk)*8 + w)*64 + lane];
  } else {
    // R254[k][b] = lastw[k][0]*c255(b) + lastw[k][1]*s255(b);
    // wave ww -> frag (kt=ww>>1, nt=ww&1)
    const int ww = w - 8;
    const int kt = ww >> 1, nt = ww & 1;
    const int n  = 16*nt + r;
    h2 p5 = __builtin_bit_cast(h2, phiT[255*36 + n]);
    const float cb = (float)p5[0], sb = (float)p5[1];
    uint4 o; unsigned ow[4];
    #pragma unroll
    for (int jp = 0; jp < 4; ++jp){
      const int k = 32*kt + 8*q + 2*jp;
      float2 g0 = *(const float2*)(lastw + 2*k);
      float2 g1 = *(const float2*)(lastw + 2*(k+1));
      ow[jp] = pack2h(g0.x*cb + g0.y*sb, g1.x*cb + g1.y*sb);
    }
    o.x=ow[0]; o.y=ow[1]; o.z=ow[2]; o.w=ow[3];
    *(uint4*)&Rf[((kt*2 + nt)*64 + physL)*4] = o;
    // prefetch bwd A (mid 253 -> srel 126): wave's 16-row strip (am = ww)
    const uint4* bp = (const uint4*)wsBv + TOFF_U4 + (size_t)126 * SITE_U4;
    #pragma unroll
    for (int d = 0; d < 2; ++d)
      #pragma unroll
      for (int kk = 0; kk < 4; ++kk)
        F0[d*4+kk] = bp[(size_t)((d*8 + ww)*4 + kk)*64 + lane];
  }

  // ---- Step body: fwd consumes mid[t] + phi(t+1); bwd mid[253-t] + phi(254-t) ----
  auto body = [&](int t, uint4 (&Fc)[8], uint4 (&Fn)[8]){
    __syncthreads();   // state frags for step t visible; prev-buf reads done

    if (w < 8){
      // prefetch fwd B for step t+1
      {
        const int soff = (t < 126) ? (t + 1) : 0;
        const uint4* bp = (const uint4*)wsBv + (size_t)soff * SITE_U4;
        #pragma unroll
        for (int d = 0; d < 2; ++d)
          #pragma unroll
          for (int kk = 0; kk < 4; ++kk)
            Fn[d*4+kk] = bp[(size_t)((d*4 + kk)*8 + w)*64 + lane];
      }
      v4f ac0[2] = {};   // plane 0, [mt]
      v4f ac1[2] = {};   // plane 1, [mt]
      const unsigned* Ab = &Af[(t & 1) * 2048];
      #pragma unroll
      for (int kt = 0; kt < 4; ++kt){
        uint4 a0 = *(const uint4*)&Ab[((0*4 + kt)*64 + physL)*4];
        uint4 a1 = *(const uint4*)&Ab[((1*4 + kt)*64 + physL)*4];
        ac0[0] = mfma16h(a0, Fc[0*4+kt], ac0[0]);
        ac0[1] = mfma16h(a1, Fc[0*4+kt], ac0[1]);
        ac1[0] = mfma16h(a0, Fc[1*4+kt], ac1[0]);
        ac1[1] = mfma16h(a1, Fc[1*4+kt], ac1[1]);
      }
      if (t < 126){
        // left'[b=16mt+4q+reg][l=16w+r] -> Af[(t+1)&1] frag (mt, kt'=w>>1)
        unsigned short* Wb = (unsigned short*)&Af[((t+1) & 1) * 2048];
        const int X  = 4*(w & 1) + 2*rh + (q >> 1);
        const int S0 = 32*(w & 1) + 16*rh + 4*q;
        #pragma unroll
        for (int mt = 0; mt < 2; ++mt){
          uint4 phiu = *(const uint4*)&phiT[(t+1)*36 + 16*mt + 4*q];
          const unsigned pr[4] = {phiu.x, phiu.y, phiu.z, phiu.w};
          const int base16 = (mt*4 + (w >> 1))*512;
          #pragma unroll
          for (int reg = 0; reg < 4; ++reg){
            h2 ph = __builtin_bit_cast(h2, pr[reg]);
            float v = (float)ph[0]*ac0[mt][reg] + (float)ph[1]*ac1[mt][reg];
            Wb[base16 + ((S0 + reg) ^ X)*8 + (r & 7)] = f16b(v);
          }
        }
      } else {
        // final fwd: vf = left_127-contract (phi 127 applied), combine below
        float vf[2][4];
        #pragma unroll
        for (int mt = 0; mt < 2; ++mt){
          uint4 phiu = *(const uint4*)&phiT[127*36 + 16*mt + 4*q];
          const unsigned pr[4] = {phiu.x, phiu.y, phiu.z, phiu.w};
          #pragma unroll
          for (int reg = 0; reg < 4; ++reg){
            h2 ph = __builtin_bit_cast(h2, pr[reg]);
            vf[mt][reg] = (float)ph[0]*ac0[mt][reg] + (float)ph[1]*ac1[mt][reg];
          }
        }
        if (tid < 32) scal[tid] = 0.0f;
        __syncthreads();   // Rcomb (bwd) + scal ready
        float p[2][4] = {};
        const int l = 16*w + r;
        #pragma unroll
        for (int mt = 0; mt < 2; ++mt)
          #pragma unroll
          for (int reg = 0; reg < 4; ++reg)
            p[mt][reg] = vf[mt][reg] * Rcomb[l*33 + 16*mt + 4*q + reg];
        #pragma unroll
        for (int m = 1; m < 16; m <<= 1)
          #pragma unroll
          for (int mt = 0; mt < 2; ++mt)
            #pragma unroll
            for (int reg = 0; reg < 4; ++reg)
              p[mt][reg] += __shfl_xor(p[mt][reg], m);
        if (r == 0){
          #pragma unroll
          for (int mt = 0; mt < 2; ++mt)
            #pragma unroll
            for (int reg = 0; reg < 4; ++reg)
              atomicAdd(&scal[16*mt + 4*q + reg], p[mt][reg]);
        }
      }
    } else {
      const int ww = w - 8;
      // prefetch bwd A for step t+1
      {
        const int srel = (t < 126) ? (125 - t) : 0;
        const uint4* bp = (const uint4*)wsBv + TOFF_U4 + (size_t)srel * SITE_U4;
        #pragma unroll
        for (int d = 0; d < 2; ++d)
          #pragma unroll
          for (int kk = 0; kk < 4; ++kk)
            Fn[d*4+kk] = bp[(size_t)((d*8 + ww)*4 + kk)*64 + lane];
      }
      v4f ac0[2] = {};   // plane 0, [nt]
      v4f ac1[2] = {};   // plane 1, [nt]
      const unsigned* Rb = &Rf[(t & 1) * 2048];
      #pragma unroll
      for (int kt = 0; kt < 4; ++kt){
        uint4 b0 = *(const uint4*)&Rb[((kt*2 + 0)*64 + physL)*4];
        uint4 b1 = *(const uint4*)&Rb[((kt*2 + 1)*64 + physL)*4];
        ac0[0] = mfma16h(Fc[0*4+kt], b0, ac0[0]);
        ac0[1] = mfma16h(Fc[0*4+kt], b1, ac0[1]);
        ac1[0] = mfma16h(Fc[1*4+kt], b0, ac1[0]);
        ac1[1] = mfma16h(Fc[1*4+kt], b1, ac1[1]);
      }
      const int ps = 254 - t;
      if (t < 126){
        // R'[k=16ww+4q+reg][b=16nt+r] -> Rf[(t+1)&1] frag (kt'=ww>>1, nt)
        unsigned short* Wr = (unsigned short*)&Rf[((t+1) & 1) * 2048];
        const int X = 4*(ww & 1) + 2*(q >> 1) + rh;
        const int S = (32*(ww & 1) + 16*(q >> 1) + r) ^ X;
        #pragma unroll
        for (int nt = 0; nt < 2; ++nt){
          h2 ph = __builtin_bit_cast(h2, phiT[ps*36 + 16*nt + r]);
          const float cb = (float)ph[0], sb = (float)ph[1];
          const int base = ((ww >> 1)*2 + nt)*512 + S*8 + 4*(q & 1);
          #pragma unroll
          for (int reg = 0; reg < 4; ++reg){
            float v = cb*ac0[nt][reg] + sb*ac1[nt][reg];
            Wr[base + reg] = f16b(v);
          }
        }
      } else {
        // final bwd: R_127 (phi 128 applied) -> Rcomb[l][b]
        #pragma unroll
        for (int nt = 0; nt < 2; ++nt){
          h2 ph = __builtin_bit_cast(h2, phiT[128*36 + 16*nt + r]);
          const float cb = (float)ph[0], sb = (float)ph[1];
          #pragma unroll
          for (int reg = 0; reg < 4; ++reg){
            float v = cb*ac0[nt][reg] + sb*ac1[nt][reg];
            const int l = 16*ww + 4*q + reg;
            Rcomb[l*33 + 16*nt + r] = v;
          }
        }
        if (tid < 32) scal[tid] = 0.0f;   // harmless dup with fwd path
        __syncthreads();                  // matches fwd waves' barrier
      }
    }

    if (t == 126){
      __syncthreads();   // scal complete
      for (int t2 = tid; t2 < 320; t2 += 1024){
        int bb = t2 / 10, o = t2 - bb*10;
        out[(size_t)(rowbase + bb)*10 + o] = scal[bb]*wlin[o] + blin[o];
      }
    }
  };

  #pragma unroll 1
  for (int t = 0; t < 126; t += 2){
    body(t,     F0, F1);
    body(t + 1, F1, F0);
  }
  body(126, F0, F1);
}

extern "C" void kernel_launch(void* const* d_in, const int* in_sizes, int n_in,
                              void* d_out, int out_size, void* d_ws, size_t ws_size,
                              hipStream_t stream){
  (void)in_sizes; (void)n_in; (void)out_size; (void)ws_size;
  const float* x     = (const float*)d_in[0];
  const float* first = (const float*)d_in[1];
  const float* mid   = (const float*)d_in[2];
  const float* lastw = (const float*)d_in[3];
  const float* wlin  = (const float*)d_in[4];
  const float* blin  = (const float*)d_in[5];
  float* o            = (float*)d_out;
  unsigned short* wsB = (unsigned short*)d_ws;   // 16.6 MB fp16 fragments

  hipLaunchKernelGGL(repack_mid, dim3(1016), dim3(256),  0, stream, mid, wsB);
  hipLaunchKernelGGL(mps_main,   dim3(256),  dim3(1024), 0, stream,
                     x, first, wsB, lastw, wlin, blin, o);
}